// Round 8
// baseline (104.606 us; speedup 1.0000x reference)
//
#include <hip/hip_runtime.h>
#include <hip/hip_bf16.h>

// PtrNet2: B=512, T=2048, IN=2, H=128
// Algebraic collapse (IN=2): u2[b,h,t] = mask*(x0*P0[h]+x1*P1[h]+E[h]) + wrefB[h];
//   glimpse readout = X0*P0 + X1*P1 + C*E + wrefB, X0=sum a*m*x0, X1=sum a*m*x1, C=sum a*m.
// tanh fold: sum_h vec*tanh = Vsum - sum_h (2vec)*rcp(exp2(c*arg)+1), c=2*log2(e);
//   Vsum cancels in softmax (shift-invariance) => weights = exp(-acc).
// R8: h-stationary score kernel. Wave w owns 8 h-values; their 5 coefficients are wave-uniform
//   -> readfirstlane-forced scalar loads (SGPR-resident). Base folded multiplicatively:
//   exp2(p+D) = exp2(p)*eD with eD=exp2(D) precomputed & clamped to 2^±120 (no 0*inf NaN path).
//   Inner loop: 5 VALU + 2 trans per (h,token), ZERO memory operands. Per-wave partial u to LDS
//   once per 64 tokens; stats phase sums 16 partials/token. Trans-pipe floor ~13.7 us/pass.

#define Bsz 512
#define Tsz 2048
#define Hsz 128
#define TPB 1024
#define WAVES 16
#define HPW 8     // h per wave
#define TTILE 256 // tokens per block
#define QB 8      // score blocks per batch row
#define JT (TTILE / 64)
static_assert(WAVES * HPW == Hsz, "h coverage");
static_assert(QB * TTILE == Tsz, "token tiling must cover each row exactly");
static_assert(WAVES * 64 == TPB, "wave count");

#define C2LOG2E 2.8853900817779268f
#define LOG2E   1.4426950408889634f

__device__ __forceinline__ float exp2fast(float x) { return __builtin_amdgcn_exp2f(x); }
__device__ __forceinline__ float rcpfast(float x)  { return __builtin_amdgcn_rcpf(x); }

// ---- kprep: SCB={cP0,cP1,cE,2vec}, eD0=exp2(c*(u1g0+wrefB)), UC={P0,P1,E,wrefB} ----
__global__ __launch_bounds__(128) void kprep(
        const float* __restrict__ embW, const float* __restrict__ embB,
        const float* __restrict__ encW, const float* __restrict__ encB,
        const float* __restrict__ wrefW, const float* __restrict__ wrefB,
        const float* __restrict__ wqW, const float* __restrict__ wqB,
        const float* __restrict__ dec, const float* __restrict__ vec,
        float4* __restrict__ SCB, float* __restrict__ eD0, float4* __restrict__ UC) {
    __shared__ float m0[Hsz], m1[Hsz], cc[Hsz], dq[Hsz];
    int h = threadIdx.x;
    float a0 = 0.f, a1 = 0.f, ac = 0.f;
    for (int k = 0; k < Hsz; ++k) {
        float w = encW[h * Hsz + k];
        a0 = fmaf(w, embW[2 * k + 0], a0);
        a1 = fmaf(w, embW[2 * k + 1], a1);
        ac = fmaf(w, embB[k], ac);
    }
    m0[h] = a0; m1[h] = a1; cc[h] = ac + encB[h]; dq[h] = dec[h];
    __syncthreads();
    float p0 = 0.f, p1 = 0.f, pe = 0.f, uq = wqB[h];
    for (int k = 0; k < Hsz; ++k) {
        float w = wrefW[h * Hsz + k];
        p0 = fmaf(w, m0[k], p0);
        p1 = fmaf(w, m1[k], p1);
        pe = fmaf(w, cc[k], pe);
        uq = fmaf(wqW[h * Hsz + k], dq[k], uq);
    }
    float wb = wrefB[h];
    SCB[h] = make_float4(C2LOG2E * p0, C2LOG2E * p1, C2LOG2E * pe, 2.f * vec[h]);
    float arg = C2LOG2E * (uq + wb);
    eD0[h] = exp2fast(fminf(fmaxf(arg, -120.f), 120.f));
    UC[h]  = make_float4(p0, p1, pe, wb);
}

// ---- score pass: h-stationary, register-resident coefficients; partial stats out ----
__global__ __launch_bounds__(TPB) void kscore(
        const float* __restrict__ x, const float* __restrict__ mask,
        const float4* __restrict__ SCB,
        const float* __restrict__ eDG, int bstride,   // eD0 (0) or ED1 (Hsz)
        float4* __restrict__ statsOut) {
    __shared__ float pu[WAVES][TTILE];
    __shared__ float4 wr4[4];
    int blk = blockIdx.x, tid = threadIdx.x;
    int b = blk >> 3, qb = blk & 7;
    int wv = __builtin_amdgcn_readfirstlane(tid >> 6);  // force wave-uniform -> SGPR indexing
    int lane = tid & 63;

    // wave-uniform coefficient load -> s_load -> SGPR-resident (fully unrolled, const idx)
    float cA[HPW], cB[HPW], cC[HPW], cV[HPW], cD[HPW];
    {
        const float4* cbase = SCB + wv * HPW;
        const float* dbase = eDG + (size_t)b * bstride + wv * HPW;
        #pragma unroll
        for (int i = 0; i < HPW; ++i) {
            float4 c = cbase[i];
            cA[i] = c.x; cB[i] = c.y; cC[i] = c.z; cV[i] = c.w;
            cD[i] = dbase[i];
        }
    }

    size_t tok0 = (size_t)b * Tsz + (size_t)qb * TTILE;
    const float2* x2 = (const float2*)x + tok0;
    const float* mrow = mask + tok0;

    #pragma unroll
    for (int jt = 0; jt < JT; ++jt) {
        int t = jt * 64 + lane;
        float2 xv = x2[t];
        float m = mrow[t];
        float xm0 = xv.x * m, xm1 = xv.y * m;
        float a0 = 0.f, a1 = 0.f;
        #pragma unroll
        for (int i = 0; i < HPW; i += 2) {
            // p = xm0*cA + xm1*cB + m*cC  (each VALU reads <=1 SGPR)
            float p  = fmaf(xm0, cA[i],   fmaf(xm1, cB[i],   m * cC[i]));
            float d  = fmaf(exp2fast(p),  cD[i],   1.f);
            a0 = fmaf(cV[i],   rcpfast(d),  a0);
            float p2 = fmaf(xm0, cA[i+1], fmaf(xm1, cB[i+1], m * cC[i+1]));
            float d2 = fmaf(exp2fast(p2), cD[i+1], 1.f);
            a1 = fmaf(cV[i+1], rcpfast(d2), a1);
        }
        pu[wv][t] = a0 + a1;
    }
    __syncthreads();

    // stats: token per thread (first TTILE threads); weights = exp(-acc)
    float Z = 0.f, Sm = 0.f, S0 = 0.f, S1 = 0.f;
    if (tid < TTILE) {
        float s = 0.f;
        #pragma unroll
        for (int w = 0; w < WAVES; ++w) s += pu[w][tid];
        float e = exp2fast(-LOG2E * s);
        float2 xv = x2[tid];
        float m = mrow[tid];
        float em = e * m;
        Z = e; Sm = em;
        S0 = em * xv.x; S1 = em * xv.y;
    }
    for (int off = 32; off; off >>= 1) {
        Z += __shfl_xor(Z, off); Sm += __shfl_xor(Sm, off);
        S0 += __shfl_xor(S0, off); S1 += __shfl_xor(S1, off);
    }
    if (lane == 0 && wv < 4) wr4[wv] = make_float4(Z, Sm, S0, S1);
    __syncthreads();
    if (tid == 0) {
        float4 s0 = wr4[0], s1 = wr4[1], s2 = wr4[2], s3 = wr4[3];
        statsOut[blk] = make_float4(s0.x + s1.x + s2.x + s3.x,
                                    s0.y + s1.y + s2.y + s3.y,
                                    s0.z + s1.z + s2.z + s3.z,
                                    s0.w + s1.w + s2.w + s3.w);
    }
}

// ---- kmid: combine glimpse-0 partials -> trip -> u1 matvec -> ED1[b][h] ----
__global__ __launch_bounds__(128) void kmid(
        const float4* __restrict__ statsA, const float4* __restrict__ UC,
        const float* __restrict__ wqW, const float* __restrict__ wqB,
        float* __restrict__ ED1) {
    __shared__ float q[Hsz];
    int b = blockIdx.x, tid = threadIdx.x;
    float Z = 0.f, Sm = 0.f, S0 = 0.f, S1 = 0.f;
    #pragma unroll
    for (int i = 0; i < QB; ++i) {
        float4 t = statsA[b * QB + i];   // uniform -> s_load
        Z += t.x; Sm += t.y; S0 += t.z; S1 += t.w;
    }
    float inv = 1.f / Z;
    float X0 = S0 * inv, X1 = S1 * inv, Cm = Sm * inv;
    float4 u4 = UC[tid];
    q[tid] = fmaf(X0, u4.x, fmaf(X1, u4.y, fmaf(Cm, u4.z, u4.w)));
    __syncthreads();
    float s = wqB[tid];
    const float* wr = wqW + (size_t)tid * Hsz;
    #pragma unroll 8
    for (int k = 0; k < Hsz; ++k) s = fmaf(wr[k], q[k], s);
    float arg = C2LOG2E * (s + u4.w);
    ED1[b * Hsz + tid] = exp2fast(fminf(fmaxf(arg, -120.f), 120.f));
}

// ---- kfin: combine glimpse-1 partials -> trip -> relu(fc1 q) -> fc2 -> out ----
__global__ __launch_bounds__(128) void kfin(
        const float4* __restrict__ statsB, const float4* __restrict__ UC,
        const float* __restrict__ fc1, const float* __restrict__ fc2,
        float* __restrict__ out) {
    __shared__ float q[Hsz], rr[Hsz];
    int b = blockIdx.x, tid = threadIdx.x;
    float Z = 0.f, Sm = 0.f, S0 = 0.f, S1 = 0.f;
    #pragma unroll
    for (int i = 0; i < QB; ++i) {
        float4 t = statsB[b * QB + i];
        Z += t.x; Sm += t.y; S0 += t.z; S1 += t.w;
    }
    float inv = 1.f / Z;
    float X0 = S0 * inv, X1 = S1 * inv, Cm = Sm * inv;
    float4 u4 = UC[tid];
    q[tid] = fmaf(X0, u4.x, fmaf(X1, u4.y, fmaf(Cm, u4.z, u4.w)));
    __syncthreads();
    float s = 0.f;
    const float* fr = fc1 + (size_t)tid * Hsz;
    #pragma unroll 8
    for (int k = 0; k < Hsz; ++k) s = fmaf(fr[k], q[k], s);
    rr[tid] = fmaxf(s, 0.f);
    __syncthreads();
    int o = tid >> 6, l = tid & 63;
    float s2 = fc2[o * Hsz + l] * rr[l] + fc2[o * Hsz + 64 + l] * rr[64 + l];
    for (int off = 32; off; off >>= 1) s2 += __shfl_xor(s2, off);
    if (l == 0) out[b * 2 + o] = s2;
}

extern "C" void kernel_launch(void* const* d_in, const int* in_sizes, int n_in,
                              void* d_out, int out_size, void* d_ws, size_t ws_size,
                              hipStream_t stream) {
    const float* x     = (const float*)d_in[0];
    const float* mask  = (const float*)d_in[1];
    const float* embW  = (const float*)d_in[2];
    const float* embB  = (const float*)d_in[3];
    const float* encW  = (const float*)d_in[4];
    const float* encB  = (const float*)d_in[5];
    const float* dec   = (const float*)d_in[6];
    const float* vec   = (const float*)d_in[7];
    const float* wqW   = (const float*)d_in[8];
    const float* wqB   = (const float*)d_in[9];
    const float* wrefW = (const float*)d_in[10];
    const float* wrefB = (const float*)d_in[11];
    const float* fc1   = (const float*)d_in[12];
    const float* fc2   = (const float*)d_in[13];

    float* ws = (float*)d_ws;
    float4* SCB    = (float4*)(ws + 0);       // 128 float4 = 512 floats
    float4* UC     = (float4*)(ws + 512);     // 512
    float*  eD0    = ws + 1024;               // 128 (pad to 1536)
    float*  ED1    = ws + 1536;               // Bsz*Hsz = 65536 -> ends 67072
    float4* statsA = (float4*)(ws + 67072);   // Bsz*QB float4 = 16384 floats
    float4* statsB = (float4*)(ws + 83456);   // 16384 floats; total ~390 KB
    float* out = (float*)d_out;

    kprep<<<1, 128, 0, stream>>>(embW, embB, encW, encB, wrefW, wrefB, wqW, wqB,
                                 dec, vec, SCB, eD0, UC);
    kscore<<<Bsz * QB, TPB, 0, stream>>>(x, mask, SCB, eD0, 0, statsA);
    kmid<<<Bsz, 128, 0, stream>>>(statsA, UC, wqW, wqB, ED1);
    kscore<<<Bsz * QB, TPB, 0, stream>>>(x, mask, SCB, ED1, Hsz, statsB);
    kfin<<<Bsz, 128, 0, stream>>>(statsB, UC, fc1, fc2, out);
}

// Round 9
// 92.186 us; speedup vs baseline: 1.1347x; 1.1347x over previous
//
#include <hip/hip_runtime.h>
#include <hip/hip_bf16.h>

// PtrNet2: B=512, T=2048, IN=2, H=128
// Algebraic collapse (IN=2): u2[b,h,t] = mask*(x0*P0[h]+x1*P1[h]+E[h]) + wrefB[h];
//   glimpse readout = X0*P0 + X1*P1 + C*E + wrefB, X0=sum a*m*x0, X1=sum a*m*x1, C=sum a*m.
// tanh fold: sum_h vec*tanh = Vsum - sum_h (2vec)*rcp(exp2(c*arg)+1), c=2*log2(e);
//   Vsum cancels in softmax (shift-invariance) => weights = exp(-acc).
// R9: R7 structure + inner math (measured-best 31.5 busy-cyc/elem), regeared TOK=4/QB=2:
//   per-wave LDS broadcast ops halve (2.1M -> 1.05M/pass; LDS pipe ~15us < VALU ~27us)
//   and 4 independent sigma-chains/thread double ILP. No readlane (R6), no SGPR coefs (R8),
//   no forced launch bounds (R4). Geometry static_asserted (R5).

#define Bsz 512
#define Tsz 2048
#define Hsz 128
#define THR 256
#define TOK 4
#define QB 2   // score blocks per batch row
static_assert(QB * THR * TOK == Tsz, "token tiling must cover each row exactly");

#define C2LOG2E 2.8853900817779268f
#define LOG2E   1.4426950408889634f

__device__ __forceinline__ float exp2fast(float x) { return __builtin_amdgcn_exp2f(x); }
__device__ __forceinline__ float rcpfast(float x)  { return __builtin_amdgcn_rcpf(x); }

// ---- kprep: SCA={cP0,cP1,cE,base0}, UC={P0,P1,E,wrefB}, V2G=2*vec ----
__global__ __launch_bounds__(128) void kprep(
        const float* __restrict__ embW, const float* __restrict__ embB,
        const float* __restrict__ encW, const float* __restrict__ encB,
        const float* __restrict__ wrefW, const float* __restrict__ wrefB,
        const float* __restrict__ wqW, const float* __restrict__ wqB,
        const float* __restrict__ dec, const float* __restrict__ vec,
        float4* __restrict__ SCA, float4* __restrict__ UC, float* __restrict__ V2G) {
    __shared__ float m0[Hsz], m1[Hsz], cc[Hsz], dq[Hsz];
    int h = threadIdx.x;
    float a0 = 0.f, a1 = 0.f, ac = 0.f;
    for (int k = 0; k < Hsz; ++k) {
        float w = encW[h * Hsz + k];
        a0 = fmaf(w, embW[2 * k + 0], a0);
        a1 = fmaf(w, embW[2 * k + 1], a1);
        ac = fmaf(w, embB[k], ac);
    }
    m0[h] = a0; m1[h] = a1; cc[h] = ac + encB[h]; dq[h] = dec[h];
    __syncthreads();
    float p0 = 0.f, p1 = 0.f, pe = 0.f, uq = wqB[h];
    for (int k = 0; k < Hsz; ++k) {
        float w = wrefW[h * Hsz + k];
        p0 = fmaf(w, m0[k], p0);
        p1 = fmaf(w, m1[k], p1);
        pe = fmaf(w, cc[k], pe);
        uq = fmaf(wqW[h * Hsz + k], dq[k], uq);
    }
    float wb = wrefB[h];
    SCA[h] = make_float4(C2LOG2E * p0, C2LOG2E * p1, C2LOG2E * pe, C2LOG2E * (uq + wb));
    UC[h]  = make_float4(p0, p1, pe, wb);
    V2G[h] = 2.f * vec[h];
}

// ---- score pass: one block per 1024 tokens; LDS-broadcast coefficients; partial stats out ----
__global__ __launch_bounds__(THR) void kscore(
        const float* __restrict__ x, const float* __restrict__ mask,
        const float4* __restrict__ quadG, int bstride,   // 0 (shared) or Hsz (per-b table)
        const float* __restrict__ V2G,
        float4* __restrict__ statsOut) {
    __shared__ float4 quad[Hsz];
    __shared__ float v2s[Hsz];
    __shared__ float4 wr4[THR / 64];
    int blk = blockIdx.x, tid = threadIdx.x;
    int b = blk >> 1, qb = blk & 1;
    int wave = tid >> 6, lane = tid & 63;
    if (tid < Hsz) {
        quad[tid] = quadG[(size_t)b * bstride + tid];
        v2s[tid] = V2G[tid];
    }

    size_t tok0 = (size_t)b * Tsz + (size_t)qb * (THR * TOK);
    const float2* x2 = (const float2*)(x + tok0 * 2);
    const float* mrow = mask + tok0;
    float xm0[TOK], xm1[TOK], mk[TOK];
    #pragma unroll
    for (int j = 0; j < TOK; ++j) {
        float2 xv = x2[j * THR + tid];
        float m = mrow[j * THR + tid];
        mk[j] = m; xm0[j] = xv.x * m; xm1[j] = xv.y * m;
    }
    __syncthreads();

    float acc[TOK] = {0.f, 0.f, 0.f, 0.f};
    #pragma unroll 4
    for (int h = 0; h < Hsz; ++h) {
        float4 qd = quad[h];
        float vv = v2s[h];
        #pragma unroll
        for (int j = 0; j < TOK; ++j) {
            float a = fmaf(xm0[j], qd.x, fmaf(xm1[j], qd.y, fmaf(mk[j], qd.z, qd.w)));
            acc[j] = fmaf(vv, rcpfast(exp2fast(a) + 1.f), acc[j]);
        }
    }

    // weights ∝ exp(-acc); S0 = sum e*m*x0 = sum e*xm0
    float Z = 0.f, Sm = 0.f, S0 = 0.f, S1 = 0.f;
    #pragma unroll
    for (int j = 0; j < TOK; ++j) {
        float e = exp2fast(-LOG2E * acc[j]);
        Z += e;
        Sm = fmaf(e, mk[j], Sm);
        S0 = fmaf(e, xm0[j], S0);
        S1 = fmaf(e, xm1[j], S1);
    }
    for (int off = 32; off; off >>= 1) {
        Z += __shfl_xor(Z, off); Sm += __shfl_xor(Sm, off);
        S0 += __shfl_xor(S0, off); S1 += __shfl_xor(S1, off);
    }
    if (lane == 0) wr4[wave] = make_float4(Z, Sm, S0, S1);
    __syncthreads();
    if (tid == 0) {
        float4 s = wr4[0];
        #pragma unroll
        for (int w = 1; w < THR / 64; ++w) {
            s.x += wr4[w].x; s.y += wr4[w].y; s.z += wr4[w].z; s.w += wr4[w].w;
        }
        statsOut[blk] = s;
    }
}

// ---- kmid: combine glimpse-0 partials -> trip -> u1 matvec -> per-b coeff table QB1 ----
__global__ __launch_bounds__(128) void kmid(
        const float4* __restrict__ statsA, const float4* __restrict__ UC,
        const float4* __restrict__ SCA,
        const float* __restrict__ wqW, const float* __restrict__ wqB,
        float4* __restrict__ QB1) {
    __shared__ float q[Hsz];
    int b = blockIdx.x, tid = threadIdx.x;
    float Z = 0.f, Sm = 0.f, S0 = 0.f, S1 = 0.f;
    #pragma unroll
    for (int i = 0; i < QB; ++i) {
        float4 t = statsA[b * QB + i];   // uniform -> s_load
        Z += t.x; Sm += t.y; S0 += t.z; S1 += t.w;
    }
    float inv = 1.f / Z;
    float X0 = S0 * inv, X1 = S1 * inv, Cm = Sm * inv;
    float4 u4 = UC[tid];
    q[tid] = fmaf(X0, u4.x, fmaf(X1, u4.y, fmaf(Cm, u4.z, u4.w)));
    __syncthreads();
    float s = wqB[tid];
    const float* wr = wqW + (size_t)tid * Hsz;
    #pragma unroll 8
    for (int k = 0; k < Hsz; ++k) s = fmaf(wr[k], q[k], s);
    float4 sc = SCA[tid];
    QB1[b * Hsz + tid] = make_float4(sc.x, sc.y, sc.z, C2LOG2E * (s + u4.w));
}

// ---- kfin: combine glimpse-1 partials -> trip -> relu(fc1 q) -> fc2 -> out ----
__global__ __launch_bounds__(128) void kfin(
        const float4* __restrict__ statsB, const float4* __restrict__ UC,
        const float* __restrict__ fc1, const float* __restrict__ fc2,
        float* __restrict__ out) {
    __shared__ float q[Hsz], rr[Hsz];
    int b = blockIdx.x, tid = threadIdx.x;
    float Z = 0.f, Sm = 0.f, S0 = 0.f, S1 = 0.f;
    #pragma unroll
    for (int i = 0; i < QB; ++i) {
        float4 t = statsB[b * QB + i];
        Z += t.x; Sm += t.y; S0 += t.z; S1 += t.w;
    }
    float inv = 1.f / Z;
    float X0 = S0 * inv, X1 = S1 * inv, Cm = Sm * inv;
    float4 u4 = UC[tid];
    q[tid] = fmaf(X0, u4.x, fmaf(X1, u4.y, fmaf(Cm, u4.z, u4.w)));
    __syncthreads();
    float s = 0.f;
    const float* fr = fc1 + (size_t)tid * Hsz;
    #pragma unroll 8
    for (int k = 0; k < Hsz; ++k) s = fmaf(fr[k], q[k], s);
    rr[tid] = fmaxf(s, 0.f);
    __syncthreads();
    int o = tid >> 6, l = tid & 63;
    float s2 = fc2[o * Hsz + l] * rr[l] + fc2[o * Hsz + 64 + l] * rr[64 + l];
    for (int off = 32; off; off >>= 1) s2 += __shfl_xor(s2, off);
    if (l == 0) out[b * 2 + o] = s2;
}

extern "C" void kernel_launch(void* const* d_in, const int* in_sizes, int n_in,
                              void* d_out, int out_size, void* d_ws, size_t ws_size,
                              hipStream_t stream) {
    const float* x     = (const float*)d_in[0];
    const float* mask  = (const float*)d_in[1];
    const float* embW  = (const float*)d_in[2];
    const float* embB  = (const float*)d_in[3];
    const float* encW  = (const float*)d_in[4];
    const float* encB  = (const float*)d_in[5];
    const float* dec   = (const float*)d_in[6];
    const float* vec   = (const float*)d_in[7];
    const float* wqW   = (const float*)d_in[8];
    const float* wqB   = (const float*)d_in[9];
    const float* wrefW = (const float*)d_in[10];
    const float* wrefB = (const float*)d_in[11];
    const float* fc1   = (const float*)d_in[12];
    const float* fc2   = (const float*)d_in[13];

    float* ws = (float*)d_ws;
    float4* SCA    = (float4*)(ws + 0);       // 128 float4 = 512 floats
    float4* UC     = (float4*)(ws + 512);     // 512
    float*  V2G    = ws + 1024;               // 128 (pad to 1536)
    float4* QB1    = (float4*)(ws + 1536);    // Bsz*Hsz float4 = 262144 floats
    float4* statsA = (float4*)(ws + 263680);  // Bsz*QB float4 = 4096 floats
    float4* statsB = (float4*)(ws + 267776);  // 4096 floats; total ~1.06 MB
    float* out = (float*)d_out;

    kprep<<<1, 128, 0, stream>>>(embW, embB, encW, encB, wrefW, wrefB, wqW, wqB,
                                 dec, vec, SCA, UC, V2G);
    kscore<<<Bsz * QB, THR, 0, stream>>>(x, mask, SCA, 0, V2G, statsA);
    kmid<<<Bsz, 128, 0, stream>>>(statsA, UC, SCA, wqW, wqB, QB1);
    kscore<<<Bsz * QB, THR, 0, stream>>>(x, mask, QB1, Hsz, V2G, statsB);
    kfin<<<Bsz, 128, 0, stream>>>(statsB, UC, fc1, fc2, out);
}

// Round 10
// 90.711 us; speedup vs baseline: 1.1532x; 1.0163x over previous
//
#include <hip/hip_runtime.h>
#include <hip/hip_bf16.h>

// PtrNet2: B=512, T=2048, IN=2, H=128
// Algebraic collapse (IN=2): u2[b,h,t] = mask*(x0*P0[h]+x1*P1[h]+E[h]) + wrefB[h];
//   glimpse readout = X0*P0 + X1*P1 + C*E + wrefB, X0=sum a*m*x0, X1=sum a*m*x1, C=sum a*m.
// tanh fold: sum_h vec*tanh = Vsum - sum_h (2vec)*rcp(exp2(c*arg)+1), c=2*log2(e);
//   Vsum cancels in softmax (shift-invariance) => weights = exp(-acc).
// R10: trans is the bottleneck (R6-R9: wall invariant across occupancy/LDS geometry; busy fits
//   trans~12cyc/wave). Group 4 h per rcp: sum v_i/f_i = [(v0f1+v1f0)f2f3+(v2f3+v3f2)f0f1]/(f0f1f2f3)
//   -> 4 exp + 1 rcp per 4 elems (1.25 trans/elem vs 2), 6.5 VALU/elem. Exact algebra.
//   kmid folded into kscoreB (quad.w overwritten in LDS); 4 launches, no QB1 table.

#define Bsz 512
#define Tsz 2048
#define Hsz 128
#define THR 256
#define TOK 4
#define QB 2   // score blocks per batch row
static_assert(QB * THR * TOK == Tsz, "token tiling must cover each row exactly");

#define C2LOG2E 2.8853900817779268f
#define LOG2E   1.4426950408889634f

__device__ __forceinline__ float exp2fast(float x) { return __builtin_amdgcn_exp2f(x); }
__device__ __forceinline__ float rcpfast(float x)  { return __builtin_amdgcn_rcpf(x); }

// ---- kprep: SCA={cP0,cP1,cE,base0}, UC={P0,P1,E,wrefB}, V2G=2*vec ----
__global__ __launch_bounds__(128) void kprep(
        const float* __restrict__ embW, const float* __restrict__ embB,
        const float* __restrict__ encW, const float* __restrict__ encB,
        const float* __restrict__ wrefW, const float* __restrict__ wrefB,
        const float* __restrict__ wqW, const float* __restrict__ wqB,
        const float* __restrict__ dec, const float* __restrict__ vec,
        float4* __restrict__ SCA, float4* __restrict__ UC, float* __restrict__ V2G) {
    __shared__ float m0[Hsz], m1[Hsz], cc[Hsz], dq[Hsz];
    int h = threadIdx.x;
    float a0 = 0.f, a1 = 0.f, ac = 0.f;
    for (int k = 0; k < Hsz; ++k) {
        float w = encW[h * Hsz + k];
        a0 = fmaf(w, embW[2 * k + 0], a0);
        a1 = fmaf(w, embW[2 * k + 1], a1);
        ac = fmaf(w, embB[k], ac);
    }
    m0[h] = a0; m1[h] = a1; cc[h] = ac + encB[h]; dq[h] = dec[h];
    __syncthreads();
    float p0 = 0.f, p1 = 0.f, pe = 0.f, uq = wqB[h];
    for (int k = 0; k < Hsz; ++k) {
        float w = wrefW[h * Hsz + k];
        p0 = fmaf(w, m0[k], p0);
        p1 = fmaf(w, m1[k], p1);
        pe = fmaf(w, cc[k], pe);
        uq = fmaf(wqW[h * Hsz + k], dq[k], uq);
    }
    float wb = wrefB[h];
    SCA[h] = make_float4(C2LOG2E * p0, C2LOG2E * p1, C2LOG2E * pe, C2LOG2E * (uq + wb));
    UC[h]  = make_float4(p0, p1, pe, wb);
    V2G[h] = 2.f * vec[h];
}

// ---- score pass; MID: combine prev stats -> trip -> u1 matvec -> overwrite quad.w ----
template<bool MID>
__global__ __launch_bounds__(THR) void kscore(
        const float* __restrict__ x, const float* __restrict__ mask,
        const float4* __restrict__ SCA, const float* __restrict__ V2G,
        const float4* __restrict__ UC,
        const float* __restrict__ wqW, const float* __restrict__ wqB,
        const float4* __restrict__ statsIn,
        float4* __restrict__ statsOut) {
    __shared__ float4 quad[Hsz];
    __shared__ float4 v4s[Hsz / 4];
    __shared__ float qv[Hsz];
    __shared__ float4 wr4[THR / 64];
    int blk = blockIdx.x, tid = threadIdx.x;
    int b = blk >> 1, qb = blk & 1;
    int wave = tid >> 6, lane = tid & 63;
    if (tid < Hsz) quad[tid] = SCA[tid];
    if (tid < Hsz / 4) v4s[tid] = ((const float4*)V2G)[tid];

    size_t tok0 = (size_t)b * Tsz + (size_t)qb * (THR * TOK);
    const float2* x2 = (const float2*)(x + tok0 * 2);
    const float* mrow = mask + tok0;
    float xm0[TOK], xm1[TOK], mk[TOK];
    #pragma unroll
    for (int j = 0; j < TOK; ++j) {
        float2 xv = x2[j * THR + tid];
        float m = mrow[j * THR + tid];
        mk[j] = m; xm0[j] = xv.x * m; xm1[j] = xv.y * m;
    }

    if (MID) {
        // combine glimpse-0 partials (uniform -> s_load), build q, then u1 matvec
        float Zc = 0.f, Smc = 0.f, S0c = 0.f, S1c = 0.f;
        #pragma unroll
        for (int i = 0; i < QB; ++i) {
            float4 t = statsIn[b * QB + i];
            Zc += t.x; Smc += t.y; S0c += t.z; S1c += t.w;
        }
        float inv = 1.f / Zc;
        float X0 = S0c * inv, X1 = S1c * inv, Cm = Smc * inv;
        if (tid < Hsz) {
            float4 u4 = UC[tid];
            qv[tid] = fmaf(X0, u4.x, fmaf(X1, u4.y, fmaf(Cm, u4.z, u4.w)));
        }
        __syncthreads();
        if (tid < Hsz) {
            float s = wqB[tid];
            const float* wr = wqW + (size_t)tid * Hsz;
            #pragma unroll 8
            for (int k = 0; k < Hsz; ++k) s = fmaf(wr[k], qv[k], s);
            quad[tid].w = C2LOG2E * (s + UC[tid].w);  // new base
        }
    }
    __syncthreads();

    float acc[TOK] = {0.f, 0.f, 0.f, 0.f};
    #pragma unroll 2
    for (int g = 0; g < Hsz / 4; ++g) {
        float4 q0 = quad[4 * g], q1 = quad[4 * g + 1];
        float4 q2 = quad[4 * g + 2], q3 = quad[4 * g + 3];
        float4 vv = v4s[g];
        #pragma unroll
        for (int j = 0; j < TOK; ++j) {
            float p0 = fmaf(xm0[j], q0.x, fmaf(xm1[j], q0.y, fmaf(mk[j], q0.z, q0.w)));
            float p1 = fmaf(xm0[j], q1.x, fmaf(xm1[j], q1.y, fmaf(mk[j], q1.z, q1.w)));
            float p2 = fmaf(xm0[j], q2.x, fmaf(xm1[j], q2.y, fmaf(mk[j], q2.z, q2.w)));
            float p3 = fmaf(xm0[j], q3.x, fmaf(xm1[j], q3.y, fmaf(mk[j], q3.z, q3.w)));
            float f0 = exp2fast(p0) + 1.f;
            float f1 = exp2fast(p1) + 1.f;
            float f2 = exp2fast(p2) + 1.f;
            float f3 = exp2fast(p3) + 1.f;
            float AB = f0 * f1, CD = f2 * f3;
            float h01 = fmaf(vv.x, f1, vv.y * f0);
            float h23 = fmaf(vv.z, f3, vv.w * f2);
            float num = fmaf(h01, CD, h23 * AB);
            acc[j] = fmaf(num, rcpfast(AB * CD), acc[j]);
        }
    }

    // weights ∝ exp(-acc); S0 = sum e*m*x0 = sum e*xm0
    float Z = 0.f, Sm = 0.f, S0 = 0.f, S1 = 0.f;
    #pragma unroll
    for (int j = 0; j < TOK; ++j) {
        float e = exp2fast(-LOG2E * acc[j]);
        Z += e;
        Sm = fmaf(e, mk[j], Sm);
        S0 = fmaf(e, xm0[j], S0);
        S1 = fmaf(e, xm1[j], S1);
    }
    for (int off = 32; off; off >>= 1) {
        Z += __shfl_xor(Z, off); Sm += __shfl_xor(Sm, off);
        S0 += __shfl_xor(S0, off); S1 += __shfl_xor(S1, off);
    }
    if (lane == 0) wr4[wave] = make_float4(Z, Sm, S0, S1);
    __syncthreads();
    if (tid == 0) {
        float4 s = wr4[0];
        #pragma unroll
        for (int w = 1; w < THR / 64; ++w) {
            s.x += wr4[w].x; s.y += wr4[w].y; s.z += wr4[w].z; s.w += wr4[w].w;
        }
        statsOut[blk] = s;
    }
}

// ---- kfin: combine glimpse-1 partials -> trip -> relu(fc1 q) -> fc2 -> out ----
__global__ __launch_bounds__(128) void kfin(
        const float4* __restrict__ statsB, const float4* __restrict__ UC,
        const float* __restrict__ fc1, const float* __restrict__ fc2,
        float* __restrict__ out) {
    __shared__ float q[Hsz], rr[Hsz];
    int b = blockIdx.x, tid = threadIdx.x;
    float Z = 0.f, Sm = 0.f, S0 = 0.f, S1 = 0.f;
    #pragma unroll
    for (int i = 0; i < QB; ++i) {
        float4 t = statsB[b * QB + i];
        Z += t.x; Sm += t.y; S0 += t.z; S1 += t.w;
    }
    float inv = 1.f / Z;
    float X0 = S0 * inv, X1 = S1 * inv, Cm = Sm * inv;
    float4 u4 = UC[tid];
    q[tid] = fmaf(X0, u4.x, fmaf(X1, u4.y, fmaf(Cm, u4.z, u4.w)));
    __syncthreads();
    float s = 0.f;
    const float* fr = fc1 + (size_t)tid * Hsz;
    #pragma unroll 8
    for (int k = 0; k < Hsz; ++k) s = fmaf(fr[k], q[k], s);
    rr[tid] = fmaxf(s, 0.f);
    __syncthreads();
    int o = tid >> 6, l = tid & 63;
    float s2 = fc2[o * Hsz + l] * rr[l] + fc2[o * Hsz + 64 + l] * rr[64 + l];
    for (int off = 32; off; off >>= 1) s2 += __shfl_xor(s2, off);
    if (l == 0) out[b * 2 + o] = s2;
}

extern "C" void kernel_launch(void* const* d_in, const int* in_sizes, int n_in,
                              void* d_out, int out_size, void* d_ws, size_t ws_size,
                              hipStream_t stream) {
    const float* x     = (const float*)d_in[0];
    const float* mask  = (const float*)d_in[1];
    const float* embW  = (const float*)d_in[2];
    const float* embB  = (const float*)d_in[3];
    const float* encW  = (const float*)d_in[4];
    const float* encB  = (const float*)d_in[5];
    const float* dec   = (const float*)d_in[6];
    const float* vec   = (const float*)d_in[7];
    const float* wqW   = (const float*)d_in[8];
    const float* wqB   = (const float*)d_in[9];
    const float* wrefW = (const float*)d_in[10];
    const float* wrefB = (const float*)d_in[11];
    const float* fc1   = (const float*)d_in[12];
    const float* fc2   = (const float*)d_in[13];

    float* ws = (float*)d_ws;
    float4* SCA    = (float4*)(ws + 0);       // 128 float4 = 512 floats
    float4* UC     = (float4*)(ws + 512);     // 512
    float*  V2G    = ws + 1024;               // 128 (pad to 1536)
    float4* statsA = (float4*)(ws + 1536);    // Bsz*QB float4 = 4096 floats
    float4* statsB = (float4*)(ws + 5632);    // 4096 floats; total ~38 KB
    float* out = (float*)d_out;

    kprep<<<1, 128, 0, stream>>>(embW, embB, encW, encB, wrefW, wrefB, wqW, wqB,
                                 dec, vec, SCA, UC, V2G);
    kscore<false><<<Bsz * QB, THR, 0, stream>>>(x, mask, SCA, V2G, UC, wqW, wqB,
                                                nullptr, statsA);
    kscore<true><<<Bsz * QB, THR, 0, stream>>>(x, mask, SCA, V2G, UC, wqW, wqB,
                                               statsA, statsB);
    kfin<<<Bsz, 128, 0, stream>>>(statsB, UC, fc1, fc2, out);
}